// Round 12
// baseline (453.509 us; speedup 1.0000x reference)
//
#include <hip/hip_runtime.h>

#define D 64
#define CAP3 16        // type-3 capacity: deg3 ~ Poisson(2.67)
#define NBW 256        // nodes per bucket (bucket = dst >> 8)
#define QW 64          // nodes per fused block (bucket quarter)
#define EPB 2048       // edges per binA block
#define TILES 4        // src tile = src >> 14  (<= 16384 nodes = 2 MB bf16, L2-resident)
#define NBUCK 196      // ceil(50000 / 256)
#define NBINS (NBUCK * TILES)   // 784
#define BCELL 16       // LDS cell cap per (binA-block, bin): Poisson(2.6), P(>16) ~ 1e-9
#define SEGS 1536      // per-(bucket,tile) segment cap: Poisson(<=1340), +5.4 sd
#define MQCAP 768      // per-(bucket,tile,quarter) match queue: Poisson(~335), +24 sd
#define FSTRIDE 65     // facc row stride: spreads ds_add banks (65 mod 32 = 1)

__device__ __forceinline__ unsigned short f2bf(float f) {
    union { float f; unsigned u; } v; v.f = f;
    unsigned r = (v.u + 0x7FFFu + ((v.u >> 16) & 1u)) >> 16;   // RNE
    return (unsigned short)r;
}
__device__ __forceinline__ float bflo(unsigned u) {
    union { unsigned x; float f; } v; v.x = u << 16; return v.f;
}
__device__ __forceinline__ float bfhi(unsigned u) {
    union { unsigned x; float f; } v; v.x = u & 0xFFFF0000u; return v.f;
}

// ---------------- Combo: binA (blocks < nblkA) + emb-bf16 (rest) ----------------
// binA: bin edges by (dst>>8, src>>14) into LDS cells, flush each cell with one
// global cursor atomic into the bin's contiguous segment (monotone, line-dense).
// record = src | ef<<16 | (dst&255)<<19.
__global__ __launch_bounds__(256) void k_combo(
        const int* __restrict__ src, const int* __restrict__ dst, const int* __restrict__ ef,
        unsigned* __restrict__ seg, int* __restrict__ segcnt,
        const float4* __restrict__ g4, const float4* __restrict__ w4,
        unsigned short* __restrict__ embb,
        int n_edges, int nblkA, int n_elems) {
    __shared__ unsigned lcell[NBINS * BCELL];   // 50 KB
    __shared__ int lcnt[NBINS];                 //  3 KB
    int tid = threadIdx.x;

    if (blockIdx.x < (unsigned)nblkA) {
        // ---- binA ----
        int base = blockIdx.x * EPB;
        for (int i = tid; i < NBINS; i += 256) lcnt[i] = 0;
        __syncthreads();

        int e0 = base + tid * 8;
        if (e0 + 8 <= n_edges) {
            int4 d0 = *(const int4*)(dst + e0), d1 = *(const int4*)(dst + e0 + 4);
            int4 s0 = *(const int4*)(src + e0), s1 = *(const int4*)(src + e0 + 4);
            int4 f0 = *(const int4*)(ef  + e0), f1 = *(const int4*)(ef  + e0 + 4);
            int ds[8] = {d0.x, d0.y, d0.z, d0.w, d1.x, d1.y, d1.z, d1.w};
            int ss[8] = {s0.x, s0.y, s0.z, s0.w, s1.x, s1.y, s1.z, s1.w};
            int fs[8] = {f0.x, f0.y, f0.z, f0.w, f1.x, f1.y, f1.z, f1.w};
            #pragma unroll
            for (int j = 0; j < 8; ++j) {
                int b = (ds[j] >> 8) * TILES + (ss[j] >> 14);
                unsigned rec = (unsigned)ss[j] | ((unsigned)fs[j] << 16)
                             | ((unsigned)(ds[j] & 255) << 19);
                int pos = atomicAdd(&lcnt[b], 1);
                if (pos < BCELL) lcell[b * BCELL + pos] = rec;
            }
        } else {
            for (int j = 0; j < 8; ++j) {
                int e = e0 + j;
                if (e < n_edges) {
                    int d = dst[e], s = src[e];
                    int b = (d >> 8) * TILES + (s >> 14);
                    unsigned rec = (unsigned)s | ((unsigned)ef[e] << 16)
                                 | ((unsigned)(d & 255) << 19);
                    int pos = atomicAdd(&lcnt[b], 1);
                    if (pos < BCELL) lcell[b * BCELL + pos] = rec;
                }
            }
        }
        __syncthreads();

        for (int b = tid; b < NBINS; b += 256) {
            int v = lcnt[b]; if (v > BCELL) v = BCELL;
            if (v > 0) {
                int off = atomicAdd(&segcnt[b], v);
                if (off + v > SEGS) v = (SEGS > off) ? (SEGS - off) : 0;
                unsigned* dstp = seg + (size_t)b * SEGS + off;
                for (int k = 0; k < v; ++k) dstp[k] = lcell[b * BCELL + k];
            }
        }
    } else {
        // ---- emb (bf16) ----
        int i = (blockIdx.x - nblkA) * 256 + tid;       // 8 floats per thread
        if (i * 8 >= n_elems) return;
        float4 a = g4[i * 2];
        float4 b = g4[i * 2 + 1];
        float4 wa = w4[(i * 2) & 15];
        float4 wb = w4[(i * 2 + 1) & 15];
        a.x *= wa.x; a.y *= wa.y; a.z *= wa.z; a.w *= wa.w;
        b.x *= wb.x; b.y *= wb.y; b.z *= wb.z; b.w *= wb.w;
        a.x = a.x > 0.f ? a.x : (expf(a.x) - 1.f);
        a.y = a.y > 0.f ? a.y : (expf(a.y) - 1.f);
        a.z = a.z > 0.f ? a.z : (expf(a.z) - 1.f);
        a.w = a.w > 0.f ? a.w : (expf(a.w) - 1.f);
        b.x = b.x > 0.f ? b.x : (expf(b.x) - 1.f);
        b.y = b.y > 0.f ? b.y : (expf(b.y) - 1.f);
        b.z = b.z > 0.f ? b.z : (expf(b.z) - 1.f);
        b.w = b.w > 0.f ? b.w : (expf(b.w) - 1.f);
        uint4 o;
        o.x = (unsigned)f2bf(a.x) | ((unsigned)f2bf(a.y) << 16);
        o.y = (unsigned)f2bf(a.z) | ((unsigned)f2bf(a.w) << 16);
        o.z = (unsigned)f2bf(b.x) | ((unsigned)f2bf(b.y) << 16);
        o.w = (unsigned)f2bf(b.z) | ((unsigned)f2bf(b.w) << 16);
        *(uint4*)(embb + (size_t)i * 8) = o;
    }
}

// ---------------- Fused twohop: tiled record-parallel gather into LDS fp32 ----------------
// Block = (bucket, quarter). For each src-tile (2 MB bf16 window, L2-resident):
// scan the (bucket,tile) sub-segment, enqueue my quarter's records in LDS,
// then drain 8 records/wave-round: 8 lanes load the 128 B emb row and
// ds_add_f32 into facc. Finally convert facc -> ftb (bf16) + emit ell3/cnt3.
__global__ __launch_bounds__(512) void k_fuse(
        const unsigned short* __restrict__ embb,
        const unsigned* __restrict__ seg, const int* __restrict__ segcnt,
        unsigned short* __restrict__ ftb, int* __restrict__ cnt3, unsigned* __restrict__ ell3,
        int n_nodes) {
    __shared__ float facc[QW * FSTRIDE];    // 16.25 KB
    __shared__ unsigned lpay3[QW * CAP3];   //  4 KB
    __shared__ int lc3[QW];
    __shared__ unsigned mq[MQCAP];          //  3 KB
    __shared__ int mqc;
    int bucket = blockIdx.x >> 2;
    int q      = blockIdx.x & 3;
    int lo     = bucket * NBW + q * QW;
    int tid  = threadIdx.x;
    int wave = tid >> 6, lane = tid & 63;
    int grp = lane >> 3, sub = lane & 7;

    for (int i = tid; i < QW * FSTRIDE; i += 512) facc[i] = 0.f;
    for (int i = tid; i < QW; i += 512) lc3[i] = 0;

    for (int t = 0; t < TILES; ++t) {
        __syncthreads();                 // covers init / previous drain
        if (tid == 0) mqc = 0;
        __syncthreads();
        int bin = bucket * TILES + t;
        int cnt = segcnt[bin]; if (cnt > SEGS) cnt = SEGS;
        const unsigned* sp = seg + (size_t)bin * SEGS;
        for (int i = tid; i < cnt; i += 512) {
            unsigned rec = sp[i];
            unsigned r = rec >> 19;
            if ((int)(r >> 6) == q) {
                int pos = atomicAdd(&mqc, 1);
                if (pos < MQCAP) mq[pos] = rec;
                if (((rec >> 16) & 7u) == 3u) {
                    unsigned rr = r & 63u;
                    int p3 = atomicAdd(&lc3[rr], 1);
                    if (p3 < CAP3) lpay3[rr * CAP3 + p3] = rec & 0xFFFFu;
                }
            }
        }
        __syncthreads();
        int m = mqc; if (m > MQCAP) m = MQCAP;
        #pragma unroll 2
        for (int j = wave * 8; j < m; j += 64) {
            int idx = j + grp;
            if (idx < m) {
                unsigned rec = mq[idx];                       // LDS broadcast per 8 lanes
                unsigned rr = (rec >> 19) & 63u;
                int s  = rec & 0xFFFF;
                int et = (rec >> 16) & 7;
                float sc = (et == 0 || et == 4 || et == 5) ? 2.f : 1.f;
                uint4 u = *(const uint4*)(embb + (size_t)s * D + sub * 8);
                float* fp = facc + rr * FSTRIDE + sub * 8;
                atomicAdd(fp + 0, bflo(u.x) * sc);
                atomicAdd(fp + 1, bfhi(u.x) * sc);
                atomicAdd(fp + 2, bflo(u.y) * sc);
                atomicAdd(fp + 3, bfhi(u.y) * sc);
                atomicAdd(fp + 4, bflo(u.z) * sc);
                atomicAdd(fp + 5, bfhi(u.z) * sc);
                atomicAdd(fp + 6, bflo(u.w) * sc);
                atomicAdd(fp + 7, bfhi(u.w) * sc);
            }
        }
    }
    __syncthreads();

    // ftb writeout: thread -> (node = tid/8, dim octet = tid%8)
    {
        int n  = tid >> 3;
        int dd = (tid & 7) * 8;
        int node = lo + n;
        if (node < n_nodes) {
            const float* fp = facc + n * FSTRIDE + dd;
            uint4 o;
            o.x = (unsigned)f2bf(fp[0]) | ((unsigned)f2bf(fp[1]) << 16);
            o.y = (unsigned)f2bf(fp[2]) | ((unsigned)f2bf(fp[3]) << 16);
            o.z = (unsigned)f2bf(fp[4]) | ((unsigned)f2bf(fp[5]) << 16);
            o.w = (unsigned)f2bf(fp[6]) | ((unsigned)f2bf(fp[7]) << 16);
            *(uint4*)(ftb + (size_t)node * D + dd) = o;
        }
    }
    for (int i = tid; i < QW; i += 512) {
        int node = lo + i;
        if (node < n_nodes) cnt3[node] = lc3[i] < CAP3 ? lc3[i] : CAP3;
    }
    for (int i = tid; i < QW * CAP3; i += 512) {
        int node = lo + (i >> 4);
        if (node < n_nodes) ell3[(size_t)node * CAP3 + (i & 15)] = lpay3[i];
    }
}

// ---------------- Pass 3: out[n] = sum ftb[src] over type-3 in-edges ----------------
__global__ void k_onehop_gather(const unsigned short* __restrict__ ftb,
                                const int* __restrict__ cnt3,
                                const unsigned* __restrict__ ell3,
                                float* __restrict__ out, int n_nodes) {
    int gid  = blockIdx.x * blockDim.x + threadIdx.x;
    int node = gid >> 6;
    int lane = gid & 63;
    if (node >= n_nodes) return;
    int deg = cnt3[node];
    const unsigned* row = ell3 + (size_t)node * CAP3;
    int grp = lane >> 3;
    int sub = lane & 7;
    int dq8 = sub * 8;
    int e0 = grp, e1 = grp + 8;
    int i0 = 0, i1 = 0;
    float s0 = 0.f, s1 = 0.f;
    if (e0 < deg) { i0 = row[e0] & 0xFFFF; s0 = 1.f; }
    if (e1 < deg) { i1 = row[e1] & 0xFFFF; s1 = 1.f; }
    uint4 u0 = *(const uint4*)(ftb + (size_t)i0 * D + dq8);
    uint4 u1 = *(const uint4*)(ftb + (size_t)i1 * D + dq8);
    float acc0 = bflo(u0.x) * s0 + bflo(u1.x) * s1;
    float acc1 = bfhi(u0.x) * s0 + bfhi(u1.x) * s1;
    float acc2 = bflo(u0.y) * s0 + bflo(u1.y) * s1;
    float acc3 = bfhi(u0.y) * s0 + bfhi(u1.y) * s1;
    float acc4 = bflo(u0.z) * s0 + bflo(u1.z) * s1;
    float acc5 = bfhi(u0.z) * s0 + bfhi(u1.z) * s1;
    float acc6 = bflo(u0.w) * s0 + bflo(u1.w) * s1;
    float acc7 = bfhi(u0.w) * s0 + bfhi(u1.w) * s1;
    #pragma unroll
    for (int m = 8; m <= 32; m <<= 1) {
        acc0 += __shfl_xor(acc0, m); acc1 += __shfl_xor(acc1, m);
        acc2 += __shfl_xor(acc2, m); acc3 += __shfl_xor(acc3, m);
        acc4 += __shfl_xor(acc4, m); acc5 += __shfl_xor(acc5, m);
        acc6 += __shfl_xor(acc6, m); acc7 += __shfl_xor(acc7, m);
    }
    if (grp == 0) {
        float4 oa = {acc0, acc1, acc2, acc3};
        float4 ob = {acc4, acc5, acc6, acc7};
        *(float4*)(out + (size_t)node * D + dq8)     = oa;
        *(float4*)(out + (size_t)node * D + dq8 + 4) = ob;
    }
}

extern "C" void kernel_launch(void* const* d_in, const int* in_sizes, int n_in,
                              void* d_out, int out_size, void* d_ws, size_t ws_size,
                              hipStream_t stream) {
    const float* g   = (const float*)d_in[0];   // [N, 64]
    const float* w   = (const float*)d_in[1];   // [1, 64]
    const int*   src = (const int*)d_in[2];     // [E]
    const int*   dst = (const int*)d_in[3];     // [E]
    const int*   ef  = (const int*)d_in[4];     // [E]
    float* out = (float*)d_out;

    int n_elems = in_sizes[0];                  // N * 64
    int n_nodes = n_elems / D;                  // N = 50000
    int n_edges = in_sizes[2];                  // E = 800000
    int nblkA   = (n_edges + EPB - 1) / EPB;    // 391
    int nb      = (n_nodes + NBW - 1) / NBW;    // 196
    int npad    = nb * NBW;                     // 50176 (padded node count)

    // workspace layout (~21 MB)
    unsigned short* embb   = (unsigned short*)d_ws;                  // n_elems bf16
    unsigned short* ftb    = embb + n_elems;                         // n_elems bf16
    int*            cnt3   = (int*)(ftb + n_elems);                  // npad
    int*            segcnt = cnt3 + npad;                            // NBINS
    unsigned*       ell3   = (unsigned*)(segcnt + NBINS + 64);       // npad * CAP3
    unsigned*       seg    = ell3 + (size_t)npad * CAP3;             // NBINS * SEGS

    hipMemsetAsync(segcnt, 0, (size_t)NBINS * sizeof(int), stream);

    {
        int embBlocks = (n_elems / 8 + 255) / 256;
        k_combo<<<nblkA + embBlocks, 256, 0, stream>>>(
            src, dst, ef, seg, segcnt,
            (const float4*)g, (const float4*)w, embb,
            n_edges, nblkA, n_elems);
    }
    k_fuse<<<nb * 4, 512, 0, stream>>>(embb, seg, segcnt, ftb, cnt3, ell3, n_nodes);
    {
        long long total = (long long)n_nodes * D;
        int blocks = (int)((total + 255) / 256);
        k_onehop_gather<<<blocks, 256, 0, stream>>>(ftb, cnt3, ell3, out, n_nodes);
    }
}

// Round 13
// 128.673 us; speedup vs baseline: 3.5245x; 3.5245x over previous
//
#include <hip/hip_runtime.h>

#define D 64
#define CAP 48      // per-node payload capacity: deg ~ Poisson(16), P(>48)*50k ~ 3e-6
#define CAP3 16     // type-3 capacity: deg3 ~ Poisson(2.67)
#define NBW 256     // nodes per bucket (bucket = dst >> 8)
#define QW 32       // nodes per fused block (bucket EIGHTH: finer blocks -> better tail balance)
#define EPB 2048    // edges per pass-A block
#define CELL 40     // LDS cell capacity per (blockA,bucket): Poisson(10.5), P(>40) ~ 1e-12
#define SEGSTRIDE 4608  // per-bucket segment capacity: Poisson(4082), sd~64, huge margin

__device__ __forceinline__ unsigned short f2bf(float f) {
    union { float f; unsigned u; } v; v.f = f;
    unsigned r = (v.u + 0x7FFFu + ((v.u >> 16) & 1u)) >> 16;   // RNE
    return (unsigned short)r;
}
__device__ __forceinline__ float bf2f(unsigned short h) {
    union { unsigned u; float f; } v; v.u = ((unsigned)h) << 16;
    return v.f;
}

// ---------------- Combo: binA (blocks < nblkA) + emb-bf16 (rest) ----------------
// binA: bin edges by dst>>8 into LDS cells, flush each cell with one global
// cursor atomic into the bucket's contiguous segment (monotone -> line-dense).
// record = src | ef<<16 | (dst&255)<<19.
__global__ __launch_bounds__(256) void k_combo(
        const int* __restrict__ src, const int* __restrict__ dst, const int* __restrict__ ef,
        unsigned* __restrict__ seg, int* __restrict__ segcnt,
        const float4* __restrict__ g4, const float4* __restrict__ w4,
        unsigned short* __restrict__ embb,
        int n_edges, int nb, int nblkA, int n_elems) {
    __shared__ unsigned lcell[256 * CELL];   // 40 KB
    __shared__ int lcnt[256];
    int tid = threadIdx.x;

    if (blockIdx.x < (unsigned)nblkA) {
        // ---- binA ----
        int base = blockIdx.x * EPB;
        lcnt[tid] = 0;
        __syncthreads();

        int e0 = base + tid * 8;
        if (e0 + 8 <= n_edges) {
            int4 d0 = *(const int4*)(dst + e0), d1 = *(const int4*)(dst + e0 + 4);
            int4 s0 = *(const int4*)(src + e0), s1 = *(const int4*)(src + e0 + 4);
            int4 f0 = *(const int4*)(ef  + e0), f1 = *(const int4*)(ef  + e0 + 4);
            int ds[8] = {d0.x, d0.y, d0.z, d0.w, d1.x, d1.y, d1.z, d1.w};
            int ss[8] = {s0.x, s0.y, s0.z, s0.w, s1.x, s1.y, s1.z, s1.w};
            int fs[8] = {f0.x, f0.y, f0.z, f0.w, f1.x, f1.y, f1.z, f1.w};
            #pragma unroll
            for (int j = 0; j < 8; ++j) {
                int b = ds[j] >> 8;
                unsigned rec = (unsigned)ss[j] | ((unsigned)fs[j] << 16)
                             | ((unsigned)(ds[j] & 255) << 19);
                int pos = atomicAdd(&lcnt[b], 1);
                if (pos < CELL) lcell[b * CELL + pos] = rec;
            }
        } else {
            for (int j = 0; j < 8; ++j) {
                int e = e0 + j;
                if (e < n_edges) {
                    int d = dst[e];
                    unsigned rec = (unsigned)src[e] | ((unsigned)ef[e] << 16)
                                 | ((unsigned)(d & 255) << 19);
                    int pos = atomicAdd(&lcnt[d >> 8], 1);
                    if (pos < CELL) lcell[(d >> 8) * CELL + pos] = rec;
                }
            }
        }
        __syncthreads();

        if (tid < nb) {
            int v = lcnt[tid]; if (v > CELL) v = CELL;
            if (v > 0) {
                int off = atomicAdd(&segcnt[tid], v);
                unsigned* dstp = seg + (size_t)tid * SEGSTRIDE + off;
                for (int k = 0; k < v; ++k) dstp[k] = lcell[tid * CELL + k];
            }
        }
    } else {
        // ---- emb (bf16) ----
        int i = (blockIdx.x - nblkA) * 256 + tid;       // 8 floats per thread
        if (i * 8 >= n_elems) return;
        float4 a = g4[i * 2];
        float4 b = g4[i * 2 + 1];
        float4 wa = w4[(i * 2) & 15];
        float4 wb = w4[(i * 2 + 1) & 15];
        a.x *= wa.x; a.y *= wa.y; a.z *= wa.z; a.w *= wa.w;
        b.x *= wb.x; b.y *= wb.y; b.z *= wb.z; b.w *= wb.w;
        a.x = a.x > 0.f ? a.x : (expf(a.x) - 1.f);
        a.y = a.y > 0.f ? a.y : (expf(a.y) - 1.f);
        a.z = a.z > 0.f ? a.z : (expf(a.z) - 1.f);
        a.w = a.w > 0.f ? a.w : (expf(a.w) - 1.f);
        b.x = b.x > 0.f ? b.x : (expf(b.x) - 1.f);
        b.y = b.y > 0.f ? b.y : (expf(b.y) - 1.f);
        b.z = b.z > 0.f ? b.z : (expf(b.z) - 1.f);
        b.w = b.w > 0.f ? b.w : (expf(b.w) - 1.f);
        uint4 o;
        o.x = (unsigned)f2bf(a.x) | ((unsigned)f2bf(a.y) << 16);
        o.y = (unsigned)f2bf(a.z) | ((unsigned)f2bf(a.w) << 16);
        o.z = (unsigned)f2bf(b.x) | ((unsigned)f2bf(b.y) << 16);
        o.w = (unsigned)f2bf(b.z) | ((unsigned)f2bf(b.w) << 16);
        *(uint4*)(embb + (size_t)i * 8) = o;
    }
}

// ---------------- Fused: LDS rows + twohop gather (bf16) + ell3 writeout ----------------
// Block = (bucket, eighth): 32 nodes, 256 threads (4 waves). Phase 1: uint4
// contiguous scan of the bucket segment (8x redundant, L2-resident, ~2 us
// aggregate). Phase 2: round-10 proven quad-gather, register accumulate.
__global__ __launch_bounds__(256) void k_fuse(
        const unsigned short* __restrict__ embb,
        const unsigned* __restrict__ seg, const int* __restrict__ segcnt,
        unsigned short* __restrict__ ftb, int* __restrict__ cnt3, unsigned* __restrict__ ell3,
        int nb, int n_nodes) {
    __shared__ unsigned lpay[QW * CAP];    // 6 KB
    __shared__ unsigned lpay3[QW * CAP3];  // 2 KB
    __shared__ int lc[QW];
    __shared__ int lc3[QW];
    int bucket = blockIdx.x >> 3;
    int q      = blockIdx.x & 7;
    int lo     = bucket * NBW + q * QW;
    int tid = threadIdx.x;
    int wave = tid >> 6, lane = tid & 63;
    for (int i = tid; i < QW; i += 256) { lc[i] = 0; lc3[i] = 0; }
    __syncthreads();

    // Phase 1: uint4 scan of my bucket's segment (4 records/lane)
    int total = segcnt[bucket];
    if (total > SEGSTRIDE) total = SEGSTRIDE;
    const unsigned* segp = seg + (size_t)bucket * SEGSTRIDE;
    int total4 = total & ~3;
    for (int i = tid * 4; i < total4; i += 256 * 4) {
        uint4 rv = *(const uint4*)(segp + i);
        unsigned rs[4] = {rv.x, rv.y, rv.z, rv.w};
        #pragma unroll
        for (int k = 0; k < 4; ++k) {
            unsigned rec = rs[k];
            unsigned r = rec >> 19;
            if ((int)(r >> 5) == q) {
                unsigned rr = r & 31;
                unsigned pl = rec & 0x7FFFFu;
                int pos = atomicAdd(&lc[rr], 1);
                if (pos < CAP) lpay[rr * CAP + pos] = pl;
                if (((rec >> 16) & 7u) == 3u) {
                    int p3 = atomicAdd(&lc3[rr], 1);
                    if (p3 < CAP3) lpay3[rr * CAP3 + p3] = pl;
                }
            }
        }
    }
    if (tid < (total - total4)) {          // tail (<=3 records)
        unsigned rec = segp[total4 + tid];
        unsigned r = rec >> 19;
        if ((int)(r >> 5) == q) {
            unsigned rr = r & 31;
            unsigned pl = rec & 0x7FFFFu;
            int pos = atomicAdd(&lc[rr], 1);
            if (pos < CAP) lpay[rr * CAP + pos] = pl;
            if (((rec >> 16) & 7u) == 3u) {
                int p3 = atomicAdd(&lc3[rr], 1);
                if (p3 < CAP3) lpay3[rr * CAP3 + p3] = pl;
            }
        }
    }
    __syncthreads();

    // Phase 2: quad-gather per node (bf16 rows, 128 B each), write ftb + ell3
    int grp = lane >> 4;          // 4 edge-slot groups x 16 lanes
    int dq  = (lane & 15) * 4;
    #pragma unroll 2
    for (int n = wave; n < QW; n += 4) {
        int node = lo + n;
        if (node >= n_nodes) break;
        int deg = lc[n]; deg = deg < CAP ? deg : CAP;
        const unsigned* row = lpay + n * CAP;
        float4 acc = {0.f, 0.f, 0.f, 0.f};
        for (int base = 0; base < deg; base += 16) {
            int e0 = base + grp, e1 = e0 + 4, e2 = e0 + 8, e3 = e0 + 12;
            int i0 = 0, i1 = 0, i2 = 0, i3 = 0;
            float s0 = 0.f, s1 = 0.f, s2 = 0.f, s3 = 0.f;
            if (e0 < deg) { unsigned p = row[e0]; i0 = p & 0xFFFF; int et = p >> 16;
                            s0 = 1.f + (float)(et == 0) + (float)(et == 4) + (float)(et == 5); }
            if (e1 < deg) { unsigned p = row[e1]; i1 = p & 0xFFFF; int et = p >> 16;
                            s1 = 1.f + (float)(et == 0) + (float)(et == 4) + (float)(et == 5); }
            if (e2 < deg) { unsigned p = row[e2]; i2 = p & 0xFFFF; int et = p >> 16;
                            s2 = 1.f + (float)(et == 0) + (float)(et == 4) + (float)(et == 5); }
            if (e3 < deg) { unsigned p = row[e3]; i3 = p & 0xFFFF; int et = p >> 16;
                            s3 = 1.f + (float)(et == 0) + (float)(et == 4) + (float)(et == 5); }
            ushort4 u0 = *(const ushort4*)(embb + (size_t)i0 * D + dq);
            ushort4 u1 = *(const ushort4*)(embb + (size_t)i1 * D + dq);
            ushort4 u2 = *(const ushort4*)(embb + (size_t)i2 * D + dq);
            ushort4 u3 = *(const ushort4*)(embb + (size_t)i3 * D + dq);
            acc.x += bf2f(u0.x) * s0 + bf2f(u1.x) * s1 + bf2f(u2.x) * s2 + bf2f(u3.x) * s3;
            acc.y += bf2f(u0.y) * s0 + bf2f(u1.y) * s1 + bf2f(u2.y) * s2 + bf2f(u3.y) * s3;
            acc.z += bf2f(u0.z) * s0 + bf2f(u1.z) * s1 + bf2f(u2.z) * s2 + bf2f(u3.z) * s3;
            acc.w += bf2f(u0.w) * s0 + bf2f(u1.w) * s1 + bf2f(u2.w) * s2 + bf2f(u3.w) * s3;
        }
        acc.x += __shfl_xor(acc.x, 16); acc.y += __shfl_xor(acc.y, 16);
        acc.z += __shfl_xor(acc.z, 16); acc.w += __shfl_xor(acc.w, 16);
        acc.x += __shfl_xor(acc.x, 32); acc.y += __shfl_xor(acc.y, 32);
        acc.z += __shfl_xor(acc.z, 32); acc.w += __shfl_xor(acc.w, 32);
        if (grp == 0) {
            ushort4 o;
            o.x = f2bf(acc.x); o.y = f2bf(acc.y); o.z = f2bf(acc.z); o.w = f2bf(acc.w);
            *(ushort4*)(ftb + (size_t)node * D + dq) = o;
        }
        if (lane < CAP3) ell3[(size_t)node * CAP3 + lane] = lpay3[n * CAP3 + lane];
        if (lane == 0) cnt3[node] = lc3[n] < CAP3 ? lc3[n] : CAP3;
    }
}

// ---------------- Pass 3: out[n] = sum ftb[src] over type-3 in-edges ----------------
__global__ void k_onehop_gather(const unsigned short* __restrict__ ftb,
                                const int* __restrict__ cnt3,
                                const unsigned* __restrict__ ell3,
                                float* __restrict__ out, int n_nodes) {
    int gid  = blockIdx.x * blockDim.x + threadIdx.x;
    int node = gid >> 6;
    int lane = gid & 63;
    if (node >= n_nodes) return;
    int deg = cnt3[node];
    const unsigned* row = ell3 + (size_t)node * CAP3;
    int grp = lane >> 4;
    int dq  = (lane & 15) * 4;
    int e0 = grp, e1 = grp + 4, e2 = grp + 8, e3 = grp + 12;
    int i0 = 0, i1 = 0, i2 = 0, i3 = 0;
    float s0 = 0.f, s1 = 0.f, s2 = 0.f, s3 = 0.f;
    if (e0 < deg) { i0 = row[e0] & 0xFFFF; s0 = 1.f; }
    if (e1 < deg) { i1 = row[e1] & 0xFFFF; s1 = 1.f; }
    if (e2 < deg) { i2 = row[e2] & 0xFFFF; s2 = 1.f; }
    if (e3 < deg) { i3 = row[e3] & 0xFFFF; s3 = 1.f; }
    ushort4 u0 = *(const ushort4*)(ftb + (size_t)i0 * D + dq);
    ushort4 u1 = *(const ushort4*)(ftb + (size_t)i1 * D + dq);
    ushort4 u2 = *(const ushort4*)(ftb + (size_t)i2 * D + dq);
    ushort4 u3 = *(const ushort4*)(ftb + (size_t)i3 * D + dq);
    float acc0 = bf2f(u0.x) * s0 + bf2f(u1.x) * s1 + bf2f(u2.x) * s2 + bf2f(u3.x) * s3;
    float acc1 = bf2f(u0.y) * s0 + bf2f(u1.y) * s1 + bf2f(u2.y) * s2 + bf2f(u3.y) * s3;
    float acc2 = bf2f(u0.z) * s0 + bf2f(u1.z) * s1 + bf2f(u2.z) * s2 + bf2f(u3.z) * s3;
    float acc3 = bf2f(u0.w) * s0 + bf2f(u1.w) * s1 + bf2f(u2.w) * s2 + bf2f(u3.w) * s3;
    acc0 += __shfl_xor(acc0, 16); acc1 += __shfl_xor(acc1, 16);
    acc2 += __shfl_xor(acc2, 16); acc3 += __shfl_xor(acc3, 16);
    acc0 += __shfl_xor(acc0, 32); acc1 += __shfl_xor(acc1, 32);
    acc2 += __shfl_xor(acc2, 32); acc3 += __shfl_xor(acc3, 32);
    if (grp == 0) {
        float4 o = {acc0, acc1, acc2, acc3};
        *(float4*)(out + (size_t)node * D + dq) = o;
    }
}

extern "C" void kernel_launch(void* const* d_in, const int* in_sizes, int n_in,
                              void* d_out, int out_size, void* d_ws, size_t ws_size,
                              hipStream_t stream) {
    const float* g   = (const float*)d_in[0];   // [N, 64]
    const float* w   = (const float*)d_in[1];   // [1, 64]
    const int*   src = (const int*)d_in[2];     // [E]
    const int*   dst = (const int*)d_in[3];     // [E]
    const int*   ef  = (const int*)d_in[4];     // [E]
    float* out = (float*)d_out;

    int n_elems = in_sizes[0];                  // N * 64
    int n_nodes = n_elems / D;                  // N = 50000
    int n_edges = in_sizes[2];                  // E = 800000
    int nblkA   = (n_edges + EPB - 1) / EPB;    // 391
    int nb      = (n_nodes + NBW - 1) / NBW;    // 196

    // workspace layout (~20 MB)
    unsigned short* embb   = (unsigned short*)d_ws;                  // n_elems bf16
    unsigned short* ftb    = embb + n_elems;                         // n_elems bf16
    int*            cnt3   = (int*)(ftb + n_elems);                  // N
    int*            segcnt = cnt3 + n_nodes + 64;                    // nb
    unsigned*       ell3   = (unsigned*)(segcnt + nb + 64);          // N * CAP3
    unsigned*       seg    = ell3 + (size_t)n_nodes * CAP3;          // nb * SEGSTRIDE

    hipMemsetAsync(segcnt, 0, (size_t)nb * sizeof(int), stream);

    {
        int embBlocks = (n_elems / 8 + 255) / 256;
        k_combo<<<nblkA + embBlocks, 256, 0, stream>>>(
            src, dst, ef, seg, segcnt,
            (const float4*)g, (const float4*)w, embb,
            n_edges, nb, nblkA, n_elems);
    }
    k_fuse<<<nb * 8, 256, 0, stream>>>(embb, seg, segcnt, ftb, cnt3, ell3,
                                       nb, n_nodes);
    {
        long long total = (long long)n_nodes * D;
        int blocks = (int)((total + 255) / 256);
        k_onehop_gather<<<blocks, 256, 0, stream>>>(ftb, cnt3, ell3, out, n_nodes);
    }
}

// Round 14
// 126.807 us; speedup vs baseline: 3.5764x; 1.0147x over previous
//
#include <hip/hip_runtime.h>

#define D 64
#define CAP 48      // per-node payload capacity: deg ~ Poisson(16), P(>48)*50k ~ 3e-6
#define CAP3 16     // type-3 capacity: deg3 ~ Poisson(2.67)
#define NBW 256     // nodes per bucket (bucket = dst >> 8)
#define QW 32       // nodes per fused block (bucket eighth)
#define EPB 2048    // edges per pass-A block
#define CELL 40     // LDS cell capacity per (blockA,bucket): Poisson(10.5), P(>40) ~ 1e-12
#define SEGSTRIDE 4608  // per-bucket segment capacity: Poisson(4082), sd~64, huge margin

__device__ __forceinline__ unsigned short f2bf(float f) {
    union { float f; unsigned u; } v; v.f = f;
    unsigned r = (v.u + 0x7FFFu + ((v.u >> 16) & 1u)) >> 16;   // RNE
    return (unsigned short)r;
}
__device__ __forceinline__ float bf2f(unsigned short h) {
    union { unsigned u; float f; } v; v.u = ((unsigned)h) << 16;
    return v.f;
}

// ---------------- Combo: binA (blocks < nblkA) + emb-bf16 (rest) ----------------
__global__ __launch_bounds__(256) void k_combo(
        const int* __restrict__ src, const int* __restrict__ dst, const int* __restrict__ ef,
        unsigned* __restrict__ seg, int* __restrict__ segcnt,
        const float4* __restrict__ g4, const float4* __restrict__ w4,
        unsigned short* __restrict__ embb,
        int n_edges, int nb, int nblkA, int n_elems) {
    __shared__ unsigned lcell[256 * CELL];   // 40 KB
    __shared__ int lcnt[256];
    int tid = threadIdx.x;

    if (blockIdx.x < (unsigned)nblkA) {
        int base = blockIdx.x * EPB;
        lcnt[tid] = 0;
        __syncthreads();

        int e0 = base + tid * 8;
        if (e0 + 8 <= n_edges) {
            int4 d0 = *(const int4*)(dst + e0), d1 = *(const int4*)(dst + e0 + 4);
            int4 s0 = *(const int4*)(src + e0), s1 = *(const int4*)(src + e0 + 4);
            int4 f0 = *(const int4*)(ef  + e0), f1 = *(const int4*)(ef  + e0 + 4);
            int ds[8] = {d0.x, d0.y, d0.z, d0.w, d1.x, d1.y, d1.z, d1.w};
            int ss[8] = {s0.x, s0.y, s0.z, s0.w, s1.x, s1.y, s1.z, s1.w};
            int fs[8] = {f0.x, f0.y, f0.z, f0.w, f1.x, f1.y, f1.z, f1.w};
            #pragma unroll
            for (int j = 0; j < 8; ++j) {
                int b = ds[j] >> 8;
                unsigned rec = (unsigned)ss[j] | ((unsigned)fs[j] << 16)
                             | ((unsigned)(ds[j] & 255) << 19);
                int pos = atomicAdd(&lcnt[b], 1);
                if (pos < CELL) lcell[b * CELL + pos] = rec;
            }
        } else {
            for (int j = 0; j < 8; ++j) {
                int e = e0 + j;
                if (e < n_edges) {
                    int d = dst[e];
                    unsigned rec = (unsigned)src[e] | ((unsigned)ef[e] << 16)
                                 | ((unsigned)(d & 255) << 19);
                    int pos = atomicAdd(&lcnt[d >> 8], 1);
                    if (pos < CELL) lcell[(d >> 8) * CELL + pos] = rec;
                }
            }
        }
        __syncthreads();

        if (tid < nb) {
            int v = lcnt[tid]; if (v > CELL) v = CELL;
            if (v > 0) {
                int off = atomicAdd(&segcnt[tid], v);
                unsigned* dstp = seg + (size_t)tid * SEGSTRIDE + off;
                for (int k = 0; k < v; ++k) dstp[k] = lcell[tid * CELL + k];
            }
        }
    } else {
        int i = (blockIdx.x - nblkA) * 256 + tid;       // 8 floats per thread
        if (i * 8 >= n_elems) return;
        float4 a = g4[i * 2];
        float4 b = g4[i * 2 + 1];
        float4 wa = w4[(i * 2) & 15];
        float4 wb = w4[(i * 2 + 1) & 15];
        a.x *= wa.x; a.y *= wa.y; a.z *= wa.z; a.w *= wa.w;
        b.x *= wb.x; b.y *= wb.y; b.z *= wb.z; b.w *= wb.w;
        a.x = a.x > 0.f ? a.x : (expf(a.x) - 1.f);
        a.y = a.y > 0.f ? a.y : (expf(a.y) - 1.f);
        a.z = a.z > 0.f ? a.z : (expf(a.z) - 1.f);
        a.w = a.w > 0.f ? a.w : (expf(a.w) - 1.f);
        b.x = b.x > 0.f ? b.x : (expf(b.x) - 1.f);
        b.y = b.y > 0.f ? b.y : (expf(b.y) - 1.f);
        b.z = b.z > 0.f ? b.z : (expf(b.z) - 1.f);
        b.w = b.w > 0.f ? b.w : (expf(b.w) - 1.f);
        uint4 o;
        o.x = (unsigned)f2bf(a.x) | ((unsigned)f2bf(a.y) << 16);
        o.y = (unsigned)f2bf(a.z) | ((unsigned)f2bf(a.w) << 16);
        o.z = (unsigned)f2bf(b.x) | ((unsigned)f2bf(b.y) << 16);
        o.w = (unsigned)f2bf(b.z) | ((unsigned)f2bf(b.w) << 16);
        *(uint4*)(embb + (size_t)i * 8) = o;
    }
}

// ---------------- Fused: LDS rows + twohop gather (bf16, predicated) + ell3 ----------------
__global__ __launch_bounds__(256) void k_fuse(
        const unsigned short* __restrict__ embb,
        const unsigned* __restrict__ seg, const int* __restrict__ segcnt,
        unsigned short* __restrict__ ftb, int* __restrict__ cnt3, unsigned* __restrict__ ell3,
        int nb, int n_nodes) {
    __shared__ unsigned lpay[QW * CAP];    // 6 KB
    __shared__ unsigned lpay3[QW * CAP3];  // 2 KB
    __shared__ int lc[QW];
    __shared__ int lc3[QW];
    int bucket = blockIdx.x >> 3;
    int q      = blockIdx.x & 7;
    int lo     = bucket * NBW + q * QW;
    int tid = threadIdx.x;
    int wave = tid >> 6, lane = tid & 63;
    for (int i = tid; i < QW; i += 256) { lc[i] = 0; lc3[i] = 0; }
    __syncthreads();

    // Phase 1: uint4 scan of my bucket's segment (4 records/lane)
    int total = segcnt[bucket];
    if (total > SEGSTRIDE) total = SEGSTRIDE;
    const unsigned* segp = seg + (size_t)bucket * SEGSTRIDE;
    int total4 = total & ~3;
    for (int i = tid * 4; i < total4; i += 256 * 4) {
        uint4 rv = *(const uint4*)(segp + i);
        unsigned rs[4] = {rv.x, rv.y, rv.z, rv.w};
        #pragma unroll
        for (int k = 0; k < 4; ++k) {
            unsigned rec = rs[k];
            unsigned r = rec >> 19;
            if ((int)(r >> 5) == q) {
                unsigned rr = r & 31;
                unsigned pl = rec & 0x7FFFFu;
                int pos = atomicAdd(&lc[rr], 1);
                if (pos < CAP) lpay[rr * CAP + pos] = pl;
                if (((rec >> 16) & 7u) == 3u) {
                    int p3 = atomicAdd(&lc3[rr], 1);
                    if (p3 < CAP3) lpay3[rr * CAP3 + p3] = pl;
                }
            }
        }
    }
    if (tid < (total - total4)) {
        unsigned rec = segp[total4 + tid];
        unsigned r = rec >> 19;
        if ((int)(r >> 5) == q) {
            unsigned rr = r & 31;
            unsigned pl = rec & 0x7FFFFu;
            int pos = atomicAdd(&lc[rr], 1);
            if (pos < CAP) lpay[rr * CAP + pos] = pl;
            if (((rec >> 16) & 7u) == 3u) {
                int p3 = atomicAdd(&lc3[rr], 1);
                if (p3 < CAP3) lpay3[rr * CAP3 + p3] = pl;
            }
        }
    }
    __syncthreads();

    // Phase 2: quad-gather per node; loads PREDICATED on slot < deg so dummy
    // row-gathers never issue (saves vmem slots + L1/L2 request bandwidth).
    int grp = lane >> 4;
    int dq  = (lane & 15) * 4;
    #pragma unroll 2
    for (int n = wave; n < QW; n += 4) {
        int node = lo + n;
        if (node >= n_nodes) break;
        int deg = lc[n]; deg = deg < CAP ? deg : CAP;
        const unsigned* row = lpay + n * CAP;
        float4 acc = {0.f, 0.f, 0.f, 0.f};
        for (int base = 0; base < deg; base += 16) {
            int e0 = base + grp, e1 = e0 + 4, e2 = e0 + 8, e3 = e0 + 12;
            if (e0 < deg) {
                unsigned p = row[e0]; int et = p >> 16;
                float s = 1.f + (float)(et == 0) + (float)(et == 4) + (float)(et == 5);
                ushort4 u = *(const ushort4*)(embb + (size_t)(p & 0xFFFF) * D + dq);
                acc.x += bf2f(u.x) * s; acc.y += bf2f(u.y) * s;
                acc.z += bf2f(u.z) * s; acc.w += bf2f(u.w) * s;
            }
            if (e1 < deg) {
                unsigned p = row[e1]; int et = p >> 16;
                float s = 1.f + (float)(et == 0) + (float)(et == 4) + (float)(et == 5);
                ushort4 u = *(const ushort4*)(embb + (size_t)(p & 0xFFFF) * D + dq);
                acc.x += bf2f(u.x) * s; acc.y += bf2f(u.y) * s;
                acc.z += bf2f(u.z) * s; acc.w += bf2f(u.w) * s;
            }
            if (e2 < deg) {
                unsigned p = row[e2]; int et = p >> 16;
                float s = 1.f + (float)(et == 0) + (float)(et == 4) + (float)(et == 5);
                ushort4 u = *(const ushort4*)(embb + (size_t)(p & 0xFFFF) * D + dq);
                acc.x += bf2f(u.x) * s; acc.y += bf2f(u.y) * s;
                acc.z += bf2f(u.z) * s; acc.w += bf2f(u.w) * s;
            }
            if (e3 < deg) {
                unsigned p = row[e3]; int et = p >> 16;
                float s = 1.f + (float)(et == 0) + (float)(et == 4) + (float)(et == 5);
                ushort4 u = *(const ushort4*)(embb + (size_t)(p & 0xFFFF) * D + dq);
                acc.x += bf2f(u.x) * s; acc.y += bf2f(u.y) * s;
                acc.z += bf2f(u.z) * s; acc.w += bf2f(u.w) * s;
            }
        }
        acc.x += __shfl_xor(acc.x, 16); acc.y += __shfl_xor(acc.y, 16);
        acc.z += __shfl_xor(acc.z, 16); acc.w += __shfl_xor(acc.w, 16);
        acc.x += __shfl_xor(acc.x, 32); acc.y += __shfl_xor(acc.y, 32);
        acc.z += __shfl_xor(acc.z, 32); acc.w += __shfl_xor(acc.w, 32);
        if (grp == 0) {
            ushort4 o;
            o.x = f2bf(acc.x); o.y = f2bf(acc.y); o.z = f2bf(acc.z); o.w = f2bf(acc.w);
            *(ushort4*)(ftb + (size_t)node * D + dq) = o;
        }
        if (lane < CAP3) ell3[(size_t)node * CAP3 + lane] = lpay3[n * CAP3 + lane];
        if (lane == 0) cnt3[node] = lc3[n] < CAP3 ? lc3[n] : CAP3;
    }
}

// ---------------- Pass 3: out[n] = sum ftb[src] over type-3 in-edges ----------------
// avg deg3 = 2.67 of 16 slots: predicated loads skip the ~84% dummy gathers.
__global__ void k_onehop_gather(const unsigned short* __restrict__ ftb,
                                const int* __restrict__ cnt3,
                                const unsigned* __restrict__ ell3,
                                float* __restrict__ out, int n_nodes) {
    int gid  = blockIdx.x * blockDim.x + threadIdx.x;
    int node = gid >> 6;
    int lane = gid & 63;
    if (node >= n_nodes) return;
    int deg = cnt3[node];
    const unsigned* row = ell3 + (size_t)node * CAP3;
    int grp = lane >> 4;
    int dq  = (lane & 15) * 4;
    float acc0 = 0.f, acc1 = 0.f, acc2 = 0.f, acc3 = 0.f;
    for (int e = grp; e < deg; e += 4) {
        int i = row[e] & 0xFFFF;
        ushort4 u = *(const ushort4*)(ftb + (size_t)i * D + dq);
        acc0 += bf2f(u.x); acc1 += bf2f(u.y);
        acc2 += bf2f(u.z); acc3 += bf2f(u.w);
    }
    acc0 += __shfl_xor(acc0, 16); acc1 += __shfl_xor(acc1, 16);
    acc2 += __shfl_xor(acc2, 16); acc3 += __shfl_xor(acc3, 16);
    acc0 += __shfl_xor(acc0, 32); acc1 += __shfl_xor(acc1, 32);
    acc2 += __shfl_xor(acc2, 32); acc3 += __shfl_xor(acc3, 32);
    if (grp == 0) {
        float4 o = {acc0, acc1, acc2, acc3};
        *(float4*)(out + (size_t)node * D + dq) = o;
    }
}

extern "C" void kernel_launch(void* const* d_in, const int* in_sizes, int n_in,
                              void* d_out, int out_size, void* d_ws, size_t ws_size,
                              hipStream_t stream) {
    const float* g   = (const float*)d_in[0];   // [N, 64]
    const float* w   = (const float*)d_in[1];   // [1, 64]
    const int*   src = (const int*)d_in[2];     // [E]
    const int*   dst = (const int*)d_in[3];     // [E]
    const int*   ef  = (const int*)d_in[4];     // [E]
    float* out = (float*)d_out;

    int n_elems = in_sizes[0];                  // N * 64
    int n_nodes = n_elems / D;                  // N = 50000
    int n_edges = in_sizes[2];                  // E = 800000
    int nblkA   = (n_edges + EPB - 1) / EPB;    // 391
    int nb      = (n_nodes + NBW - 1) / NBW;    // 196

    // workspace layout (~20 MB)
    unsigned short* embb   = (unsigned short*)d_ws;                  // n_elems bf16
    unsigned short* ftb    = embb + n_elems;                         // n_elems bf16
    int*            cnt3   = (int*)(ftb + n_elems);                  // N
    int*            segcnt = cnt3 + n_nodes + 64;                    // nb
    unsigned*       ell3   = (unsigned*)(segcnt + nb + 64);          // N * CAP3
    unsigned*       seg    = ell3 + (size_t)n_nodes * CAP3;          // nb * SEGSTRIDE

    hipMemsetAsync(segcnt, 0, (size_t)nb * sizeof(int), stream);

    {
        int embBlocks = (n_elems / 8 + 255) / 256;
        k_combo<<<nblkA + embBlocks, 256, 0, stream>>>(
            src, dst, ef, seg, segcnt,
            (const float4*)g, (const float4*)w, embb,
            n_edges, nb, nblkA, n_elems);
    }
    k_fuse<<<nb * 8, 256, 0, stream>>>(embb, seg, segcnt, ftb, cnt3, ell3,
                                       nb, n_nodes);
    {
        long long total = (long long)n_nodes * D;
        int blocks = (int)((total + 255) / 256);
        k_onehop_gather<<<blocks, 256, 0, stream>>>(ftb, cnt3, ell3, out, n_nodes);
    }
}